// Round 5
// baseline (1734.802 us; speedup 1.0000x reference)
//
#include <hip/hip_runtime.h>

#define HIDDEN 64
#define IN_DIM 512
#define CAP 4096      // bucket capacity (avg load ~1562 for E=1.6M, NBUCK=782)
#define NB_MAX 1024   // max buckets (n_nodes <= 131072)

typedef short v8s __attribute__((ext_vector_type(8)));
typedef float v4f __attribute__((ext_vector_type(4)));

static __device__ __forceinline__ unsigned short f2bf(float f) {
    unsigned int u = __float_as_uint(f);
    u = (u + 0x7FFF + ((u >> 16) & 1)) >> 16;   // RNE
    return (unsigned short)u;
}
static __device__ __forceinline__ float bf2f(unsigned short u) {
    return __uint_as_float(((unsigned int)u) << 16);
}
static __device__ __forceinline__ float bflo(unsigned u) { return __uint_as_float(u << 16); }
static __device__ __forceinline__ float bfhi(unsigned u) { return __uint_as_float(u & 0xffff0000u); }

// ---------------- init: zero bucket cursors + pool accumulators ------------
__global__ void k_init(int* cursor, float* gsum, int* gcnt) {
    int i = blockIdx.x * 256 + threadIdx.x;
    if (i < NB_MAX) cursor[i] = 0;
    if (i < 256) { gsum[i] = 0.f; gcnt[i] = 0; }
}

// ---------------- bin edges by dst>>7 into fixed-stride buckets ------------
// word = (src<<7) | (dst&127). Block-local LDS histogram -> one global
// atomic per (block,bin) -> LDS-slotted writes (short contiguous runs).
__launch_bounds__(256)
__global__ void k_bin(const int* __restrict__ src, const int* __restrict__ dst,
                      int* cursor, unsigned* __restrict__ bucket_data, int n_edges) {
    __shared__ unsigned words[4096];          // 16 KB
    __shared__ unsigned short binsh[4096];    // 8 KB
    __shared__ int hist[NB_MAX];              // 4 KB
    __shared__ int base[NB_MAX];              // 4 KB
    const int tid = threadIdx.x;
    const int e0 = blockIdx.x * 4096;
    for (int i = tid; i < NB_MAX; i += 256) hist[i] = 0;
    __syncthreads();
    for (int i = tid; i < 4096; i += 256) {
        int e = e0 + i;
        if (e < n_edges) {
            int d = dst[e], s = src[e];
            words[i] = ((unsigned)s << 7) | (unsigned)(d & 127);
            int b = d >> 7;
            binsh[i] = (unsigned short)b;
            atomicAdd(&hist[b], 1);
        } else binsh[i] = 0xFFFFu;
    }
    __syncthreads();
    for (int b = tid; b < NB_MAX; b += 256) {
        int c = hist[b];
        base[b] = c ? atomicAdd(&cursor[b], c) : 0;
        hist[b] = 0;
    }
    __syncthreads();
    for (int i = tid; i < 4096; i += 256) {
        unsigned short b = binsh[i];
        if (b != 0xFFFFu) {
            int slot = atomicAdd(&hist[b], 1);
            int p = base[b] + slot;
            if (p < CAP) bucket_data[(size_t)b * CAP + p] = words[i];
        }
    }
}

// ---------------- per-bucket degree count -> dinv --------------------------
__global__ void k_dinvb(const unsigned* __restrict__ bucket_data, const int* __restrict__ cursor,
                        float* __restrict__ dinv, int n_nodes) {
    __shared__ int cnt[128];
    const int tid = threadIdx.x, bin = blockIdx.x;
    if (tid < 128) cnt[tid] = 1;               // self loop
    __syncthreads();
    int c = cursor[bin]; if (c > CAP) c = CAP;
    const unsigned* bd = bucket_data + (size_t)bin * CAP;
    for (int i = tid; i < c; i += 256) atomicAdd(&cnt[bd[i] & 127], 1);
    __syncthreads();
    if (tid < 128) {
        int n = bin * 128 + tid;
        if (n < n_nodes) dinv[n] = rsqrtf((float)cnt[tid]);
    }
}

// ---------------- W1 -> Wt bf16 transpose [64][512] ------------------------
__global__ void k_prep(const float* __restrict__ W1, unsigned short* __restrict__ Wt) {
    int idx = blockIdx.x * 256 + threadIdx.x;
    int n = idx >> 9, k = idx & 511;
    Wt[(size_t)n * 512 + k] = f2bf(W1[(size_t)k * 64 + n]);
}

// ---------------- GEMM1 (MFMA bf16): s1 = bf16(dinv .* (x @ W1)) -----------
__launch_bounds__(256)
__global__ void k_gemm1m(const float* __restrict__ x, const unsigned short* __restrict__ Wt,
                         const float* __restrict__ dinv, unsigned short* __restrict__ s1,
                         int n_nodes) {
    __shared__ __align__(16) unsigned short lX[64 * 136];
    __shared__ __align__(16) unsigned short lW[64 * 136];
    const int tid  = threadIdx.x;
    const int lane = tid & 63;
    const int w    = tid >> 6;
    const int quad = lane >> 4;
    const int m16  = lane & 15;
    const int row0 = blockIdx.x * 64;

    v4f acc[4];
#pragma unroll
    for (int b = 0; b < 4; ++b) acc[b] = (v4f){0.f, 0.f, 0.f, 0.f};

    for (int kc = 0; kc < IN_DIM; kc += 128) {
        __syncthreads();
#pragma unroll
        for (int i = 0; i < 8; ++i) {
            int fidx = tid + i * 256;
            int r  = fidx >> 5;
            int c4 = fidx & 31;
            int gr = row0 + r;
            float4 v = make_float4(0.f, 0.f, 0.f, 0.f);
            if (gr < n_nodes) v = ((const float4*)(x + (size_t)gr * IN_DIM + kc))[c4];
            ushort4 u = make_ushort4(f2bf(v.x), f2bf(v.y), f2bf(v.z), f2bf(v.w));
            *(ushort4*)(lX + r * 136 + c4 * 4) = u;
        }
#pragma unroll
        for (int i = 0; i < 4; ++i) {
            int idx = tid + i * 256;
            int n  = idx >> 4;
            int c8 = idx & 15;
            uint4 u = *(const uint4*)(Wt + (size_t)n * 512 + kc + c8 * 8);
            *(uint4*)(lW + n * 136 + c8 * 8) = u;
        }
        __syncthreads();
#pragma unroll
        for (int kk = 0; kk < 128; kk += 32) {
            v8s a = *(const v8s*)(lX + (w * 16 + m16) * 136 + kk + quad * 8);
#pragma unroll
            for (int b = 0; b < 4; ++b) {
                v8s bb = *(const v8s*)(lW + (b * 16 + m16) * 136 + kk + quad * 8);
                acc[b] = __builtin_amdgcn_mfma_f32_16x16x32_bf16(a, bb, acc[b], 0, 0, 0);
            }
        }
    }
    __syncthreads();
    float* lC = (float*)lX;
#pragma unroll
    for (int b = 0; b < 4; ++b)
#pragma unroll
        for (int r = 0; r < 4; ++r) {
            int rowt = w * 16 + quad * 4 + r;
            lC[rowt * 65 + b * 16 + m16] = acc[b][r];
        }
    __syncthreads();
#pragma unroll
    for (int i = 0; i < 2; ++i) {
        int base = i * 2048 + tid * 8;
        int r = base >> 6;
        int c = base & 63;
        int gr = row0 + r;
        if (gr < n_nodes) {
            float d = dinv[gr];
            const float* p = lC + r * 65 + c;
            unsigned p0 = (unsigned)f2bf(p[0] * d) | ((unsigned)f2bf(p[1] * d) << 16);
            unsigned p1 = (unsigned)f2bf(p[2] * d) | ((unsigned)f2bf(p[3] * d) << 16);
            unsigned p2 = (unsigned)f2bf(p[4] * d) | ((unsigned)f2bf(p[5] * d) << 16);
            unsigned p3 = (unsigned)f2bf(p[6] * d) | ((unsigned)f2bf(p[7] * d) << 16);
            *(uint4*)(s1 + (size_t)gr * 64 + c) = make_uint4(p0, p1, p2, p3);
        }
    }
}

// ---------------- layer1: bucket aggregate + finalize + GEMM2 --------------
// block = one 128-node bucket; LDS fp32 accumulators; packed 4-edge gather.
__launch_bounds__(256)
__global__ void k_layer1b(const unsigned short* __restrict__ sin, const unsigned* __restrict__ bucket_data,
                          const int* __restrict__ cursor, const float* __restrict__ W2,
                          const float* __restrict__ b1, const float* __restrict__ dinv,
                          unsigned short* __restrict__ sout, int n_nodes) {
    __shared__ float accs[128 * 64];   // 32 KB
    __shared__ float ldsW[64 * 64];    // 16 KB
    __shared__ float sdinv[128];
    __shared__ float sb1[64];
    const int tid = threadIdx.x, lane = tid & 63, wave = tid >> 6;
    const int g = lane >> 4, l = lane & 15;
    const int bin = blockIdx.x, n0 = bin << 7;
    {
        const float4* Wg = (const float4*)W2; float4* Wl = (float4*)ldsW;
#pragma unroll
        for (int i = 0; i < 4; ++i) Wl[tid + i * 256] = Wg[tid + i * 256];
    }
    {
        float4 z = make_float4(0.f, 0.f, 0.f, 0.f); float4* A = (float4*)accs;
#pragma unroll
        for (int i = 0; i < 8; ++i) A[tid + i * 256] = z;
    }
    if (tid < 128) { int n = n0 + tid; sdinv[tid] = (n < n_nodes) ? dinv[n] : 0.f; }
    if (tid >= 128 && tid < 192) sb1[tid - 128] = b1[tid - 128];
    __syncthreads();
    int c = cursor[bin]; if (c > CAP) c = CAP;
    const unsigned* bd = bucket_data + (size_t)bin * CAP;
    for (int wb = wave * 64; wb < c; wb += 256) {
        int m = c - wb; if (m > 64) m = 64;
        unsigned w = (lane < m) ? bd[wb + lane] : 0u;
        if (m == 64) {
#pragma unroll 4
            for (int j = 0; j < 64; j += 4) {
                unsigned a = (unsigned)__shfl((int)w, j + g, 64);
                int s = a >> 7, dl = a & 127;
                uint2 u = *(const uint2*)(sin + (size_t)s * HIDDEN + l * 4);
                atomicAdd(&accs[dl * 64 + 4 * l + 0], bflo(u.x));
                atomicAdd(&accs[dl * 64 + 4 * l + 1], bfhi(u.x));
                atomicAdd(&accs[dl * 64 + 4 * l + 2], bflo(u.y));
                atomicAdd(&accs[dl * 64 + 4 * l + 3], bfhi(u.y));
            }
        } else {
            for (int j = 0; j < m; j += 4) {
                int myj = j + g;
                unsigned a = (unsigned)__shfl((int)w, myj, 64);
                if (myj < m) {
                    int s = a >> 7, dl = a & 127;
                    uint2 u = *(const uint2*)(sin + (size_t)s * HIDDEN + l * 4);
                    atomicAdd(&accs[dl * 64 + 4 * l + 0], bflo(u.x));
                    atomicAdd(&accs[dl * 64 + 4 * l + 1], bfhi(u.x));
                    atomicAdd(&accs[dl * 64 + 4 * l + 2], bflo(u.y));
                    atomicAdd(&accs[dl * 64 + 4 * l + 3], bfhi(u.y));
                }
            }
        }
    }
    __syncthreads();
    // h = relu(dinv*(acc+self)+b1), in place
    for (int ii = tid; ii < 128 * 16; ii += 256) {
        int n = ii >> 4, c4 = ii & 15;
        int gn = n0 + n;
        float4 A = *(float4*)&accs[n * 64 + c4 * 4];
        float4 h = make_float4(0.f, 0.f, 0.f, 0.f);
        if (gn < n_nodes) {
            uint2 u = *(const uint2*)(sin + (size_t)gn * HIDDEN + c4 * 4);
            float d = sdinv[n];
            float4 bb = ((const float4*)sb1)[c4];
            h.x = fmaxf(fmaf(d, A.x + bflo(u.x), bb.x), 0.f);
            h.y = fmaxf(fmaf(d, A.y + bfhi(u.x), bb.y), 0.f);
            h.z = fmaxf(fmaf(d, A.z + bflo(u.y), bb.z), 0.f);
            h.w = fmaxf(fmaf(d, A.w + bfhi(u.y), bb.w), 0.f);
        }
        *(float4*)&accs[n * 64 + c4 * 4] = h;
    }
    __syncthreads();
    // GEMM2: wave handles 32 nodes, k-partitioned over 4 groups
    for (int nn = wave * 32; nn < wave * 32 + 32; ++nn) {
        int gn = n0 + nn;
        if (gn >= n_nodes) break;
        float4 a4 = make_float4(0.f, 0.f, 0.f, 0.f);
#pragma unroll
        for (int kk = 0; kk < 16; ++kk) {
            float hk = accs[nn * 64 + 16 * g + kk];
            float4 w4 = *(const float4*)(ldsW + (16 * g + kk) * 64 + 4 * l);
            a4.x = fmaf(hk, w4.x, a4.x);
            a4.y = fmaf(hk, w4.y, a4.y);
            a4.z = fmaf(hk, w4.z, a4.z);
            a4.w = fmaf(hk, w4.w, a4.w);
        }
        a4.x += __shfl_xor(a4.x, 16, 64); a4.y += __shfl_xor(a4.y, 16, 64);
        a4.z += __shfl_xor(a4.z, 16, 64); a4.w += __shfl_xor(a4.w, 16, 64);
        a4.x += __shfl_xor(a4.x, 32, 64); a4.y += __shfl_xor(a4.y, 32, 64);
        a4.z += __shfl_xor(a4.z, 32, 64); a4.w += __shfl_xor(a4.w, 32, 64);
        if (g == 0) {
            float d = sdinv[nn];
            unsigned p0 = (unsigned)f2bf(a4.x * d) | ((unsigned)f2bf(a4.y * d) << 16);
            unsigned p1 = (unsigned)f2bf(a4.z * d) | ((unsigned)f2bf(a4.w * d) << 16);
            *(uint2*)(sout + (size_t)gn * HIDDEN + l * 4) = make_uint2(p0, p1);
        }
    }
}

// ---------------- layer2: bucket aggregate + finalize + Wfc dot + pool -----
__launch_bounds__(256)
__global__ void k_layer2b(const unsigned short* __restrict__ sin, const unsigned* __restrict__ bucket_data,
                          const int* __restrict__ cursor, const float* __restrict__ b2,
                          const float* __restrict__ dinv, const float* __restrict__ Wfc,
                          const int* __restrict__ batch,
                          float* gsum, int* gcnt, int n_nodes) {
    __shared__ float accs[128 * 64];   // 32 KB
    __shared__ float sdinv[128];
    __shared__ float sb2[64], swf[64];
    __shared__ int sbatch[128];
    __shared__ float lsum[256];
    __shared__ int lcnt[256];
    const int tid = threadIdx.x, lane = tid & 63, wave = tid >> 6;
    const int g = lane >> 4, l = lane & 15;
    const int bin = blockIdx.x, n0 = bin << 7;
    {
        float4 z = make_float4(0.f, 0.f, 0.f, 0.f); float4* A = (float4*)accs;
#pragma unroll
        for (int i = 0; i < 8; ++i) A[tid + i * 256] = z;
    }
    lsum[tid] = 0.f; lcnt[tid] = 0;
    if (tid < 128) {
        int n = n0 + tid;
        sdinv[tid] = (n < n_nodes) ? dinv[n] : 0.f;
        sbatch[tid] = (n < n_nodes) ? batch[n] : 0;
    }
    if (tid >= 128 && tid < 192) sb2[tid - 128] = b2[tid - 128];
    if (tid >= 192) swf[tid - 192] = Wfc[tid - 192];
    __syncthreads();
    int c = cursor[bin]; if (c > CAP) c = CAP;
    const unsigned* bd = bucket_data + (size_t)bin * CAP;
    for (int wb = wave * 64; wb < c; wb += 256) {
        int m = c - wb; if (m > 64) m = 64;
        unsigned w = (lane < m) ? bd[wb + lane] : 0u;
        if (m == 64) {
#pragma unroll 4
            for (int j = 0; j < 64; j += 4) {
                unsigned a = (unsigned)__shfl((int)w, j + g, 64);
                int s = a >> 7, dl = a & 127;
                uint2 u = *(const uint2*)(sin + (size_t)s * HIDDEN + l * 4);
                atomicAdd(&accs[dl * 64 + 4 * l + 0], bflo(u.x));
                atomicAdd(&accs[dl * 64 + 4 * l + 1], bfhi(u.x));
                atomicAdd(&accs[dl * 64 + 4 * l + 2], bflo(u.y));
                atomicAdd(&accs[dl * 64 + 4 * l + 3], bfhi(u.y));
            }
        } else {
            for (int j = 0; j < m; j += 4) {
                int myj = j + g;
                unsigned a = (unsigned)__shfl((int)w, myj, 64);
                if (myj < m) {
                    int s = a >> 7, dl = a & 127;
                    uint2 u = *(const uint2*)(sin + (size_t)s * HIDDEN + l * 4);
                    atomicAdd(&accs[dl * 64 + 4 * l + 0], bflo(u.x));
                    atomicAdd(&accs[dl * 64 + 4 * l + 1], bfhi(u.x));
                    atomicAdd(&accs[dl * 64 + 4 * l + 2], bflo(u.y));
                    atomicAdd(&accs[dl * 64 + 4 * l + 3], bfhi(u.y));
                }
            }
        }
    }
    __syncthreads();
    // t = sum_f relu(dinv*(acc+self)+b2)*Wfc ; 16-lane tree; pool into LDS bins
    for (int ii = tid; ii < 128 * 16; ii += 256) {
        int n = ii >> 4, c4 = ii & 15;
        int gn = n0 + n;
        float t = 0.f;
        if (gn < n_nodes) {
            float4 A = *(float4*)&accs[n * 64 + c4 * 4];
            uint2 u = *(const uint2*)(sin + (size_t)gn * HIDDEN + c4 * 4);
            float d = sdinv[n];
            float4 bb = ((const float4*)sb2)[c4];
            float4 wf = ((const float4*)swf)[c4];
            t = fmaxf(fmaf(d, A.x + bflo(u.x), bb.x), 0.f) * wf.x
              + fmaxf(fmaf(d, A.y + bfhi(u.x), bb.y), 0.f) * wf.y
              + fmaxf(fmaf(d, A.z + bflo(u.y), bb.z), 0.f) * wf.z
              + fmaxf(fmaf(d, A.w + bfhi(u.y), bb.w), 0.f) * wf.w;
        }
        t += __shfl_down(t, 8, 64);
        t += __shfl_down(t, 4, 64);
        t += __shfl_down(t, 2, 64);
        t += __shfl_down(t, 1, 64);
        if ((lane & 15) == 0 && gn < n_nodes) {
            atomicAdd(&lsum[sbatch[n]], t);
            atomicAdd(&lcnt[sbatch[n]], 1);
        }
    }
    __syncthreads();
    if (lcnt[tid]) {
        atomicAdd(&gsum[tid], lsum[tid]);
        atomicAdd(&gcnt[tid], lcnt[tid]);
    }
}

__global__ void k_out(const float* __restrict__ gsum, const int* __restrict__ gcnt,
                      const float* __restrict__ bfc, float* out) {
    int g = threadIdx.x;
    if (g < 256) {
        float c = (float)(gcnt[g] > 1 ? gcnt[g] : 1);
        out[g] = gsum[g] / c + bfc[0];
    }
}

// ---------------------------------------------------------------------------
extern "C" void kernel_launch(void* const* d_in, const int* in_sizes, int n_in,
                              void* d_out, int out_size, void* d_ws, size_t ws_size,
                              hipStream_t stream) {
    const float* x   = (const float*)d_in[0];
    const int*   ei  = (const int*)d_in[1];
    const int*   bat = (const int*)d_in[2];
    const float* W1  = (const float*)d_in[3];
    const float* b1  = (const float*)d_in[4];
    const float* W2  = (const float*)d_in[5];
    const float* b2  = (const float*)d_in[6];
    const float* Wfc = (const float*)d_in[7];
    const float* bfc = (const float*)d_in[8];
    float* out = (float*)d_out;

    const int n_nodes = in_sizes[2];
    const int n_edges = in_sizes[1] / 2;
    const int* src = ei;
    const int* dst = ei + n_edges;
    const int NBUCK = (n_nodes + 127) >> 7;   // <= NB_MAX for n_nodes <= 131072

    char* w = (char*)d_ws;
    size_t off = 0;
    auto alloc = [&](size_t bytes) -> void* {
        void* p = w + off;
        off += (bytes + 255) & ~(size_t)255;
        return p;
    };
    float* dinv = (float*)alloc((size_t)n_nodes * sizeof(float));
    unsigned short* bufA = (unsigned short*)alloc((size_t)n_nodes * HIDDEN * 2);
    unsigned short* bufB = (unsigned short*)alloc((size_t)n_nodes * HIDDEN * 2);
    unsigned short* Wt   = (unsigned short*)alloc((size_t)HIDDEN * IN_DIM * 2);
    float* gsum = (float*)alloc(256 * sizeof(float));
    int*   gcnt = (int*)  alloc(256 * sizeof(int));
    int*   cursor = (int*)alloc((size_t)NB_MAX * sizeof(int));
    unsigned* bucket_data = (unsigned*)alloc((size_t)NB_MAX * CAP * sizeof(unsigned));
    (void)ws_size; (void)n_in; (void)out_size;

    hipLaunchKernelGGL(k_init, dim3(NB_MAX / 256), dim3(256), 0, stream, cursor, gsum, gcnt);
    hipLaunchKernelGGL(k_bin, dim3((n_edges + 4095) / 4096), dim3(256), 0, stream,
                       src, dst, cursor, bucket_data, n_edges);
    hipLaunchKernelGGL(k_dinvb, dim3(NBUCK), dim3(256), 0, stream,
                       bucket_data, cursor, dinv, n_nodes);
    hipLaunchKernelGGL(k_prep, dim3((HIDDEN * IN_DIM) / 256), dim3(256), 0, stream, W1, Wt);
    hipLaunchKernelGGL(k_gemm1m, dim3((n_nodes + 63) / 64), dim3(256), 0, stream,
                       x, Wt, dinv, bufA, n_nodes);
    hipLaunchKernelGGL(k_layer1b, dim3(NBUCK), dim3(256), 0, stream,
                       bufA, bucket_data, cursor, W2, b1, dinv, bufB, n_nodes);
    hipLaunchKernelGGL(k_layer2b, dim3(NBUCK), dim3(256), 0, stream,
                       bufB, bucket_data, cursor, b2, dinv, Wfc, bat, gsum, gcnt, n_nodes);
    hipLaunchKernelGGL(k_out, dim3(1), dim3(256), 0, stream, gsum, gcnt, bfc, out);
}

// Round 6
// 482.503 us; speedup vs baseline: 3.5954x; 3.5954x over previous
//
#include <hip/hip_runtime.h>

#define HIDDEN 64
#define IN_DIM 512
#define CAP 4096      // bucket capacity (mean load ~2046 for E=1.6M over 782 buckets; 45 sigma headroom)
#define NB_MAX 1024   // max buckets (n_nodes <= 131072)

typedef short v8s __attribute__((ext_vector_type(8)));
typedef float v4f __attribute__((ext_vector_type(4)));

static __device__ __forceinline__ unsigned short f2bf(float f) {
    unsigned int u = __float_as_uint(f);
    u = (u + 0x7FFF + ((u >> 16) & 1)) >> 16;   // RNE
    return (unsigned short)u;
}
static __device__ __forceinline__ float bf2f(unsigned short u) {
    return __uint_as_float(((unsigned int)u) << 16);
}
static __device__ __forceinline__ float bflo(unsigned u) { return __uint_as_float(u << 16); }
static __device__ __forceinline__ float bfhi(unsigned u) { return __uint_as_float(u & 0xffff0000u); }

// ---------------- init: zero bucket cursors + pool accumulators ------------
__global__ void k_init(int* cursor, float* gsum, int* gcnt) {
    int i = blockIdx.x * 256 + threadIdx.x;
    if (i < NB_MAX) cursor[i] = 0;
    if (i < 256) { gsum[i] = 0.f; gcnt[i] = 0; }
}

// ---------------- bin edges by dst>>7 into fixed-stride buckets ------------
// word = (src<<7) | (dst&127). LDS histogram -> one global atomic per
// (block,bin) -> LDS-slotted writes (short contiguous runs, low write-amp).
__launch_bounds__(256)
__global__ void k_bin(const int* __restrict__ src, const int* __restrict__ dst,
                      int* cursor, unsigned* __restrict__ bucket_data, int n_edges) {
    __shared__ unsigned words[4096];          // 16 KB
    __shared__ unsigned short binsh[4096];    // 8 KB
    __shared__ int hist[NB_MAX];              // 4 KB
    __shared__ int base[NB_MAX];              // 4 KB
    const int tid = threadIdx.x;
    const int e0 = blockIdx.x * 4096;
    for (int i = tid; i < NB_MAX; i += 256) hist[i] = 0;
    __syncthreads();
    for (int i = tid; i < 4096; i += 256) {
        int e = e0 + i;
        if (e < n_edges) {
            int d = dst[e], s = src[e];
            words[i] = ((unsigned)s << 7) | (unsigned)(d & 127);
            int b = d >> 7;
            binsh[i] = (unsigned short)b;
            atomicAdd(&hist[b], 1);
        } else binsh[i] = 0xFFFFu;
    }
    __syncthreads();
    for (int b = tid; b < NB_MAX; b += 256) {
        int c = hist[b];
        base[b] = c ? atomicAdd(&cursor[b], c) : 0;
        hist[b] = 0;
    }
    __syncthreads();
    for (int i = tid; i < 4096; i += 256) {
        unsigned short b = binsh[i];
        if (b != 0xFFFFu) {
            int slot = atomicAdd(&hist[b], 1);
            int p = base[b] + slot;
            if (p < CAP) bucket_data[(size_t)b * CAP + p] = words[i];
        }
    }
}

// ---------------- exclusive scan of bucket counts -> bucket_base -----------
__launch_bounds__(256)
__global__ void k_bexc(const int* __restrict__ cursor, int* __restrict__ bucket_base,
                       int* __restrict__ row_start, int n_nodes, int nbuck) {
    __shared__ int wsum[4];
    const int t = threadIdx.x, lane = t & 63, w = t >> 6;
    int v[4], s = 0;
#pragma unroll
    for (int k = 0; k < 4; ++k) {
        int i = t * 4 + k;
        int c = (i < nbuck) ? cursor[i] : 0;
        if (c > CAP) c = CAP;
        v[k] = s; s += c;
    }
    int inc = s;
#pragma unroll
    for (int off = 1; off < 64; off <<= 1) {
        int u = __shfl_up(inc, off, 64);
        if (lane >= off) inc += u;
    }
    if (lane == 63) wsum[w] = inc;
    __syncthreads();
    int cross = 0;
    for (int i = 0; i < w; ++i) cross += wsum[i];
    int b0 = cross + inc - s;
#pragma unroll
    for (int k = 0; k < 4; ++k) {
        int i = t * 4 + k;
        if (i < NB_MAX) bucket_base[i] = b0 + v[k];
    }
    if (t == 255) row_start[n_nodes] = cross + inc;   // total kept edges
}

// ---------------- per-bucket CSR build (coalesced, local LDS) --------------
// block = bucket: count 128 local degrees, local scan, place edges into the
// bucket's contiguous csr region. Also emits row_start and dinv.
__launch_bounds__(256)
__global__ void k_csr(const unsigned* __restrict__ bucket_data, const int* __restrict__ cursor,
                      const int* __restrict__ bucket_base,
                      int* __restrict__ row_start, int* __restrict__ csr,
                      float* __restrict__ dinv, int n_nodes) {
    __shared__ unsigned words[CAP];   // 16 KB
    __shared__ int cnt[128];
    __shared__ int loff[128];
    __shared__ int cur[128];
    __shared__ int w0sum;
    const int tid = threadIdx.x, bin = blockIdx.x, n0 = bin << 7;
    int c = cursor[bin]; if (c > CAP) c = CAP;
    const unsigned* bd = bucket_data + (size_t)bin * CAP;
    for (int i = tid; i < c; i += 256) words[i] = bd[i];
    if (tid < 128) { cnt[tid] = 0; cur[tid] = 0; }
    __syncthreads();
    for (int i = tid; i < c; i += 256) atomicAdd(&cnt[words[i] & 127], 1);
    __syncthreads();
    int val = 0, inc = 0;
    if (tid < 128) {
        const int lane = tid & 63;
        val = cnt[tid];
        inc = val;
#pragma unroll
        for (int off = 1; off < 64; off <<= 1) {
            int u = __shfl_up(inc, off, 64);
            if (lane >= off) inc += u;
        }
        if (tid == 63) w0sum = inc;
    }
    __syncthreads();
    if (tid < 128) {
        int excl = inc - val + ((tid >= 64) ? w0sum : 0);
        loff[tid] = excl;
        int n = n0 + tid;
        if (n < n_nodes) {
            row_start[n] = bucket_base[bin] + excl;
            dinv[n] = rsqrtf((float)(val + 1));   // +1 self loop
        }
    }
    __syncthreads();
    const int gbase = bucket_base[bin];
    for (int i = tid; i < c; i += 256) {
        unsigned wd = words[i];
        int d = wd & 127;
        int slot = atomicAdd(&cur[d], 1);
        csr[gbase + loff[d] + slot] = (int)(wd >> 7);
    }
}

// ---------------- W1 -> Wt bf16 transpose [64][512] ------------------------
__global__ void k_prep(const float* __restrict__ W1, unsigned short* __restrict__ Wt) {
    int idx = blockIdx.x * 256 + threadIdx.x;
    int n = idx >> 9, k = idx & 511;
    Wt[(size_t)n * 512 + k] = f2bf(W1[(size_t)k * 64 + n]);
}

// ---------------- GEMM1 (MFMA bf16): s1 = bf16(dinv .* (x @ W1)) -----------
__launch_bounds__(256)
__global__ void k_gemm1m(const float* __restrict__ x, const unsigned short* __restrict__ Wt,
                         const float* __restrict__ dinv, unsigned short* __restrict__ s1,
                         int n_nodes) {
    __shared__ __align__(16) unsigned short lX[64 * 136];
    __shared__ __align__(16) unsigned short lW[64 * 136];
    const int tid  = threadIdx.x;
    const int lane = tid & 63;
    const int w    = tid >> 6;
    const int quad = lane >> 4;
    const int m16  = lane & 15;
    const int row0 = blockIdx.x * 64;

    v4f acc[4];
#pragma unroll
    for (int b = 0; b < 4; ++b) acc[b] = (v4f){0.f, 0.f, 0.f, 0.f};

    for (int kc = 0; kc < IN_DIM; kc += 128) {
        __syncthreads();
#pragma unroll
        for (int i = 0; i < 8; ++i) {
            int fidx = tid + i * 256;
            int r  = fidx >> 5;
            int c4 = fidx & 31;
            int gr = row0 + r;
            float4 v = make_float4(0.f, 0.f, 0.f, 0.f);
            if (gr < n_nodes) v = ((const float4*)(x + (size_t)gr * IN_DIM + kc))[c4];
            ushort4 u = make_ushort4(f2bf(v.x), f2bf(v.y), f2bf(v.z), f2bf(v.w));
            *(ushort4*)(lX + r * 136 + c4 * 4) = u;
        }
#pragma unroll
        for (int i = 0; i < 4; ++i) {
            int idx = tid + i * 256;
            int n  = idx >> 4;
            int c8 = idx & 15;
            uint4 u = *(const uint4*)(Wt + (size_t)n * 512 + kc + c8 * 8);
            *(uint4*)(lW + n * 136 + c8 * 8) = u;
        }
        __syncthreads();
#pragma unroll
        for (int kk = 0; kk < 128; kk += 32) {
            v8s a = *(const v8s*)(lX + (w * 16 + m16) * 136 + kk + quad * 8);
#pragma unroll
            for (int b = 0; b < 4; ++b) {
                v8s bb = *(const v8s*)(lW + (b * 16 + m16) * 136 + kk + quad * 8);
                acc[b] = __builtin_amdgcn_mfma_f32_16x16x32_bf16(a, bb, acc[b], 0, 0, 0);
            }
        }
    }
    __syncthreads();
    float* lC = (float*)lX;
#pragma unroll
    for (int b = 0; b < 4; ++b)
#pragma unroll
        for (int r = 0; r < 4; ++r) {
            int rowt = w * 16 + quad * 4 + r;
            lC[rowt * 65 + b * 16 + m16] = acc[b][r];
        }
    __syncthreads();
#pragma unroll
    for (int i = 0; i < 2; ++i) {
        int base = i * 2048 + tid * 8;
        int r = base >> 6;
        int c = base & 63;
        int gr = row0 + r;
        if (gr < n_nodes) {
            float d = dinv[gr];
            const float* p = lC + r * 65 + c;
            unsigned p0 = (unsigned)f2bf(p[0] * d) | ((unsigned)f2bf(p[1] * d) << 16);
            unsigned p1 = (unsigned)f2bf(p[2] * d) | ((unsigned)f2bf(p[3] * d) << 16);
            unsigned p2 = (unsigned)f2bf(p[4] * d) | ((unsigned)f2bf(p[5] * d) << 16);
            unsigned p3 = (unsigned)f2bf(p[6] * d) | ((unsigned)f2bf(p[7] * d) << 16);
            *(uint4*)(s1 + (size_t)gr * 64 + c) = make_uint4(p0, p1, p2, p3);
        }
    }
}

// ---------------- layer1: packed CSR gather + finalize + GEMM2 -------------
// wave = 4 groups x 16 lanes; lane holds features 4l..4l+3.
#define NPW 4   // nodes per wave

__launch_bounds__(256)
__global__ void k_layer1(const unsigned short* __restrict__ sin, const int* __restrict__ row_start,
                         const int* __restrict__ csr, const float* __restrict__ W2,
                         const float* __restrict__ b1, const float* __restrict__ dinv,
                         unsigned short* __restrict__ sout, int n_nodes) {
    __shared__ float ldsW[HIDDEN * HIDDEN];   // [k][f] 16 KB
    const int tid = threadIdx.x;
    {
        const float4* Wg = (const float4*)W2;
        float4* Wl = (float4*)ldsW;
#pragma unroll
        for (int i = 0; i < 4; ++i) Wl[tid + i * 256] = Wg[tid + i * 256];
    }
    __syncthreads();
    const int lane = tid & 63;
    const int wave = tid >> 6;
    const int g = lane >> 4;
    const int l = lane & 15;
    const float4 b4 = ((const float4*)b1)[l];
    const int n0 = (blockIdx.x * 4 + wave) * NPW;
    for (int i = 0; i < NPW; ++i) {
        int n = n0 + i;
        if (n >= n_nodes) break;
        int rs = row_start[n], re = row_start[n + 1];
        float4 acc = make_float4(0.f, 0.f, 0.f, 0.f);   // group-partial
        for (int base = rs; base < re; base += 64) {
            int idx = csr[base + lane];
            int m = re - base; if (m > 64) m = 64;
            for (int j = 0; j < m; j += 4) {
                int myj = j + g;
                int a = __shfl(idx, myj, 64);
                if (myj < m) {
                    uint2 u = *(const uint2*)(sin + (size_t)a * HIDDEN + l * 4);
                    acc.x += bflo(u.x); acc.y += bfhi(u.x);
                    acc.z += bflo(u.y); acc.w += bfhi(u.y);
                }
            }
        }
        acc.x += __shfl_xor(acc.x, 16, 64); acc.y += __shfl_xor(acc.y, 16, 64);
        acc.z += __shfl_xor(acc.z, 16, 64); acc.w += __shfl_xor(acc.w, 16, 64);
        acc.x += __shfl_xor(acc.x, 32, 64); acc.y += __shfl_xor(acc.y, 32, 64);
        acc.z += __shfl_xor(acc.z, 32, 64); acc.w += __shfl_xor(acc.w, 32, 64);
        {
            uint2 u = *(const uint2*)(sin + (size_t)n * HIDDEN + l * 4);
            acc.x += bflo(u.x); acc.y += bfhi(u.x);
            acc.z += bflo(u.y); acc.w += bfhi(u.y);
        }
        float d = dinv[n];
        float4 h;
        h.x = fmaxf(fmaf(d, acc.x, b4.x), 0.f);
        h.y = fmaxf(fmaf(d, acc.y, b4.y), 0.f);
        h.z = fmaxf(fmaf(d, acc.z, b4.z), 0.f);
        h.w = fmaxf(fmaf(d, acc.w, b4.w), 0.f);
        // GEMM2, k-partitioned: group g handles k = 16g..16g+15
        float4 a4 = make_float4(0.f, 0.f, 0.f, 0.f);
#pragma unroll
        for (int kk = 0; kk < 16; ++kk) {
            int srcl = 4 * g + (kk >> 2);
            float hk;
            if ((kk & 3) == 0)      hk = __shfl(h.x, srcl, 64);
            else if ((kk & 3) == 1) hk = __shfl(h.y, srcl, 64);
            else if ((kk & 3) == 2) hk = __shfl(h.z, srcl, 64);
            else                    hk = __shfl(h.w, srcl, 64);
            float4 w4 = *(const float4*)(ldsW + (16 * g + kk) * HIDDEN + 4 * l);
            a4.x = fmaf(hk, w4.x, a4.x);
            a4.y = fmaf(hk, w4.y, a4.y);
            a4.z = fmaf(hk, w4.z, a4.z);
            a4.w = fmaf(hk, w4.w, a4.w);
        }
        a4.x += __shfl_xor(a4.x, 16, 64); a4.y += __shfl_xor(a4.y, 16, 64);
        a4.z += __shfl_xor(a4.z, 16, 64); a4.w += __shfl_xor(a4.w, 16, 64);
        a4.x += __shfl_xor(a4.x, 32, 64); a4.y += __shfl_xor(a4.y, 32, 64);
        a4.z += __shfl_xor(a4.z, 32, 64); a4.w += __shfl_xor(a4.w, 32, 64);
        if (g == 0) {
            unsigned p0 = (unsigned)f2bf(a4.x * d) | ((unsigned)f2bf(a4.y * d) << 16);
            unsigned p1 = (unsigned)f2bf(a4.z * d) | ((unsigned)f2bf(a4.w * d) << 16);
            *(uint2*)(sout + (size_t)n * HIDDEN + l * 4) = make_uint2(p0, p1);
        }
    }
}

// ---------------- layer2: packed CSR gather + finalize + Wfc dot + pool ----
__launch_bounds__(256)
__global__ void k_layer2pool(const unsigned short* __restrict__ sin, const int* __restrict__ row_start,
                             const int* __restrict__ csr, const float* __restrict__ b2,
                             const float* __restrict__ dinv, const float* __restrict__ Wfc,
                             const int* __restrict__ batch,
                             float* gsum, int* gcnt, int n_nodes) {
    __shared__ float lsum[256];
    __shared__ int   lcnt[256];
    const int tid = threadIdx.x;
    lsum[tid] = 0.f; lcnt[tid] = 0;
    __syncthreads();
    const int lane = tid & 63;
    const int wave = tid >> 6;
    const int g = lane >> 4;
    const int l = lane & 15;
    const float4 b4  = ((const float4*)b2)[l];
    const float4 wf4 = ((const float4*)Wfc)[l];
    const int n0 = (blockIdx.x * 4 + wave) * NPW;
    for (int i = 0; i < NPW; ++i) {
        int n = n0 + i;
        if (n >= n_nodes) break;
        int rs = row_start[n], re = row_start[n + 1];
        float4 acc = make_float4(0.f, 0.f, 0.f, 0.f);
        for (int base = rs; base < re; base += 64) {
            int idx = csr[base + lane];
            int m = re - base; if (m > 64) m = 64;
            for (int j = 0; j < m; j += 4) {
                int myj = j + g;
                int a = __shfl(idx, myj, 64);
                if (myj < m) {
                    uint2 u = *(const uint2*)(sin + (size_t)a * HIDDEN + l * 4);
                    acc.x += bflo(u.x); acc.y += bfhi(u.x);
                    acc.z += bflo(u.y); acc.w += bfhi(u.y);
                }
            }
        }
        acc.x += __shfl_xor(acc.x, 16, 64); acc.y += __shfl_xor(acc.y, 16, 64);
        acc.z += __shfl_xor(acc.z, 16, 64); acc.w += __shfl_xor(acc.w, 16, 64);
        acc.x += __shfl_xor(acc.x, 32, 64); acc.y += __shfl_xor(acc.y, 32, 64);
        acc.z += __shfl_xor(acc.z, 32, 64); acc.w += __shfl_xor(acc.w, 32, 64);
        {
            uint2 u = *(const uint2*)(sin + (size_t)n * HIDDEN + l * 4);
            acc.x += bflo(u.x); acc.y += bfhi(u.x);
            acc.z += bflo(u.y); acc.w += bfhi(u.y);
        }
        float d = dinv[n];
        float t = fmaxf(fmaf(d, acc.x, b4.x), 0.f) * wf4.x
                + fmaxf(fmaf(d, acc.y, b4.y), 0.f) * wf4.y
                + fmaxf(fmaf(d, acc.z, b4.z), 0.f) * wf4.z
                + fmaxf(fmaf(d, acc.w, b4.w), 0.f) * wf4.w;
#pragma unroll
        for (int off = 32; off; off >>= 1) t += __shfl_down(t, off, 64);
        if (lane == 0) {
            int gr = batch[n];
            atomicAdd(&lsum[gr], t * 0.25f);   // groups replicate features 4x
            atomicAdd(&lcnt[gr], 1);
        }
    }
    __syncthreads();
    if (lcnt[tid]) {
        atomicAdd(&gsum[tid], lsum[tid]);
        atomicAdd(&gcnt[tid], lcnt[tid]);
    }
}

__global__ void k_out(const float* __restrict__ gsum, const int* __restrict__ gcnt,
                      const float* __restrict__ bfc, float* out) {
    int g = threadIdx.x;
    if (g < 256) {
        float c = (float)(gcnt[g] > 1 ? gcnt[g] : 1);
        out[g] = gsum[g] / c + bfc[0];
    }
}

// ---------------------------------------------------------------------------
extern "C" void kernel_launch(void* const* d_in, const int* in_sizes, int n_in,
                              void* d_out, int out_size, void* d_ws, size_t ws_size,
                              hipStream_t stream) {
    const float* x   = (const float*)d_in[0];
    const int*   ei  = (const int*)d_in[1];
    const int*   bat = (const int*)d_in[2];
    const float* W1  = (const float*)d_in[3];
    const float* b1  = (const float*)d_in[4];
    const float* W2  = (const float*)d_in[5];
    const float* b2  = (const float*)d_in[6];
    const float* Wfc = (const float*)d_in[7];
    const float* bfc = (const float*)d_in[8];
    float* out = (float*)d_out;

    const int n_nodes = in_sizes[2];
    const int n_edges = in_sizes[1] / 2;
    const int* src = ei;
    const int* dst = ei + n_edges;
    const int NBUCK = (n_nodes + 127) >> 7;

    char* w = (char*)d_ws;
    size_t off = 0;
    auto alloc = [&](size_t bytes) -> void* {
        void* p = w + off;
        off += (bytes + 255) & ~(size_t)255;
        return p;
    };
    float* dinv = (float*)alloc((size_t)n_nodes * sizeof(float));
    unsigned short* bufA = (unsigned short*)alloc((size_t)n_nodes * HIDDEN * 2);
    unsigned short* bufB = (unsigned short*)alloc((size_t)n_nodes * HIDDEN * 2);
    unsigned short* Wt   = (unsigned short*)alloc((size_t)HIDDEN * IN_DIM * 2);
    float* gsum = (float*)alloc(256 * sizeof(float));
    int*   gcnt = (int*)  alloc(256 * sizeof(int));
    int*   cursor      = (int*)alloc((size_t)NB_MAX * sizeof(int));
    int*   bucket_base = (int*)alloc((size_t)NB_MAX * sizeof(int));
    unsigned* bucket_data = (unsigned*)alloc((size_t)NB_MAX * CAP * sizeof(unsigned));
    int* row_start = (int*)alloc(((size_t)n_nodes + 1) * sizeof(int));
    int* csr       = (int*)alloc(((size_t)n_edges + 64) * sizeof(int));
    (void)ws_size; (void)n_in; (void)out_size;

    hipLaunchKernelGGL(k_init, dim3(NB_MAX / 256), dim3(256), 0, stream, cursor, gsum, gcnt);
    hipLaunchKernelGGL(k_bin, dim3((n_edges + 4095) / 4096), dim3(256), 0, stream,
                       src, dst, cursor, bucket_data, n_edges);
    hipLaunchKernelGGL(k_bexc, dim3(1), dim3(256), 0, stream,
                       cursor, bucket_base, row_start, n_nodes, NBUCK);
    hipLaunchKernelGGL(k_csr, dim3(NBUCK), dim3(256), 0, stream,
                       bucket_data, cursor, bucket_base, row_start, csr, dinv, n_nodes);
    hipLaunchKernelGGL(k_prep, dim3((HIDDEN * IN_DIM) / 256), dim3(256), 0, stream, W1, Wt);
    hipLaunchKernelGGL(k_gemm1m, dim3((n_nodes + 63) / 64), dim3(256), 0, stream,
                       x, Wt, dinv, bufA, n_nodes);
    const int gb = (n_nodes + 4 * NPW - 1) / (4 * NPW);
    hipLaunchKernelGGL(k_layer1, dim3(gb), dim3(256), 0, stream,
                       bufA, row_start, csr, W2, b1, dinv, bufB, n_nodes);
    hipLaunchKernelGGL(k_layer2pool, dim3(gb), dim3(256), 0, stream,
                       bufB, row_start, csr, b2, dinv, Wfc, bat, gsum, gcnt, n_nodes);
    hipLaunchKernelGGL(k_out, dim3(1), dim3(256), 0, stream, gsum, gcnt, bfc, out);
}